// Round 4
// baseline (335.145 us; speedup 1.0000x reference)
//
#include <hip/hip_runtime.h>

#define N_ATOMS 10000
#define N_EDGES 160000
#define N_STRUCT 8
#define D_PAD 48             // padded slots per atom; P(Poisson(16) > 48) ~ 2e-7 overall
#define EDW 48               // floats per slot: [0..15]=sh, [16..31]=R, [32..47]=hs
#define N_SLOTS (N_ATOMS * D_PAD)
#define PI_F 3.14159265358979323846f

#define WLDS 1088            // floats of LDS per wave (epilogue scratch only)

// ---------------- setup ----------------

__global__ void init_kernel(float* __restrict__ edat, int* __restrict__ snd,
                            int* __restrict__ cursor, float* __restrict__ accum) {
    int i = blockIdx.x * blockDim.x + threadIdx.x;
    if (i < N_SLOTS) {
        float4 z = make_float4(0.f, 0.f, 0.f, 0.f);
        float4* p = (float4*)(edat + (size_t)i * EDW);
        p[0] = z; p[1] = z; p[2] = z; p[3] = z;
        snd[i] = 0;
    }
    if (i < N_ATOMS) cursor[i] = i * D_PAD;
    if (i < N_STRUCT) accum[i] = 0.f;
}

__global__ void scatter_kernel(const int* __restrict__ receivers, int* __restrict__ cursor,
                               int* __restrict__ perm) {
    int e = blockIdx.x * blockDim.x + threadIdx.x;
    if (e < N_EDGES) perm[e] = atomicAdd(&cursor[receivers[e]], 1);
}

__global__ void emb_kernel(const float* __restrict__ embed, const int* __restrict__ species,
                           float* __restrict__ h0) {
    int i = blockIdx.x * blockDim.x + threadIdx.x;
    if (i < N_ATOMS * 16) {
        int a = i >> 4, c = i & 15;
        h0[i] = embed[species[a] * 16 + c];
    }
}

__global__ void gather_h(const int* __restrict__ snd, const float* __restrict__ h,
                         float* __restrict__ edat) {
    int g = blockIdx.x * blockDim.x + threadIdx.x;
    if (g < N_SLOTS * 4) {
        int slot = g >> 2, seg = g & 3;
        int s = snd[slot];
        *(float4*)(edat + (size_t)slot * EDW + 32 + seg * 4) =
            *(const float4*)(h + (size_t)s * 16 + seg * 4);
    }
}

// transpose W_inv [256,16] -> W_invT [16,256] so the per-wave epilogue matmul
// reads contiguous float4 rows (both layers in one tiny launch)
__global__ void transpose_winv(const float* __restrict__ A, const float* __restrict__ B,
                               float* __restrict__ AT, float* __restrict__ BT) {
    int i = blockIdx.x * blockDim.x + threadIdx.x;
    if (i < 4096) {
        int k = i >> 4, c = i & 15;
        AT[c * 256 + k] = A[i];
    } else if (i < 8192) {
        int j = i - 4096;
        int k = j >> 4, c = j & 15;
        BT[c * 256 + k] = B[j];
    }
}

// ---------------- edge geometry -> padded slots ----------------

__global__ void edge_geom(const float* __restrict__ pos, const float* __restrict__ W_rad,
                          const int* __restrict__ senders, const int* __restrict__ receivers,
                          const int* __restrict__ perm,
                          float* __restrict__ edat, int* __restrict__ snd) {
    int e = blockIdx.x * blockDim.x + threadIdx.x;
    if (e >= N_EDGES) return;
    int s = senders[e], rc = receivers[e];
    int p = perm[e];
    float dx = pos[rc * 3 + 0] - pos[s * 3 + 0];
    float dy = pos[rc * 3 + 1] - pos[s * 3 + 1];
    float dz = pos[rc * 3 + 2] - pos[s * 3 + 2];
    float r = sqrtf(dx * dx + dy * dy + dz * dz);
    float rr = fmaxf(r, 1e-6f);
    float inv = 1.0f / rr;
    float x = dx * inv, y = dy * inv, z = dz * inv;
    float x2 = x * x, y2 = y * y, z2 = z * z;
    float she[16];
    she[0]  = 0.28209479f;
    she[1]  = 0.48860251f * y;
    she[2]  = 0.48860251f * z;
    she[3]  = 0.48860251f * x;
    she[4]  = 1.09254843f * x * y;
    she[5]  = 1.09254843f * y * z;
    she[6]  = 0.31539157f * (3.0f * z2 - 1.0f);
    she[7]  = 1.09254843f * x * z;
    she[8]  = 0.54627422f * (x2 - y2);
    she[9]  = 0.59004359f * y * (3.0f * x2 - y2);
    she[10] = 2.89061144f * x * y * z;
    she[11] = 0.45704579f * y * (5.0f * z2 - 1.0f);
    she[12] = 0.37317633f * z * (5.0f * z2 - 3.0f);
    she[13] = 0.45704579f * x * (5.0f * z2 - 1.0f);
    she[14] = 1.44530572f * z * (x2 - y2);
    she[15] = 0.59004359f * x * (x2 - 3.0f * y2);
    float* ed = edat + (size_t)p * EDW;
    ((float4*)ed)[0] = make_float4(she[0], she[1], she[2], she[3]);
    ((float4*)ed)[1] = make_float4(she[4], she[5], she[6], she[7]);
    ((float4*)ed)[2] = make_float4(she[8], she[9], she[10], she[11]);
    ((float4*)ed)[3] = make_float4(she[12], she[13], she[14], she[15]);
    float fc = 0.5f * (cosf(PI_F * fminf(r * 0.2f, 1.0f)) + 1.0f);
    const float c0 = 0.6324555320336759f; // sqrt(2/5)
    float bfv[8];
    #pragma unroll
    for (int n = 0; n < 8; ++n)
        bfv[n] = c0 * sinf((float)(n + 1) * PI_F * rr * 0.2f) * inv * fc;
    float Re[16];
    #pragma unroll
    for (int l = 0; l < 4; ++l) {
        #pragma unroll
        for (int n = 0; n < 4; ++n) {
            float acc = 0.0f;
            #pragma unroll
            for (int b = 0; b < 8; ++b) acc = fmaf(bfv[b], W_rad[l * 32 + b * 4 + n], acc);
            Re[l * 4 + n] = acc;
        }
    }
    ((float4*)ed)[4] = make_float4(Re[0], Re[1], Re[2], Re[3]);
    ((float4*)ed)[5] = make_float4(Re[4], Re[5], Re[6], Re[7]);
    ((float4*)ed)[6] = make_float4(Re[8], Re[9], Re[10], Re[11]);
    ((float4*)ed)[7] = make_float4(Re[12], Re[13], Re[14], Re[15]);
    snd[p] = s;
}

// ---------------- fused MP layer: one wave per atom, DIRECT global loads ----------------
// R0/R3 both staged the strip through global_load_lds and both stuck at ~140 us
// (VALU 9%, HBM 5%, latency-bound). The strip has ZERO cross-wave reuse; intra-wave
// broadcast is served by L1 line-coalescing. So: no LDS staging, no DMA, no hand
// waitcnts -- each lane loads its own sh/R/hs slices straight to registers and the
// compiler software-pipelines the fully-unrolled 48-slot loop. LDS holds only the
// 1088-float/wave epilogue scratch. 256-thread blocks (4 atoms), per-wave epilogue.

__global__ __launch_bounds__(256, 4) void mp_layer(
    const float* __restrict__ edat,
    const float* __restrict__ W_invT,
    const float* __restrict__ cemb, float* __restrict__ h_out,
    const float* __restrict__ w_out, const float* __restrict__ comp_w,
    const int* __restrict__ species, const int* __restrict__ sids,
    float* __restrict__ accum, int do_energy)
{
    __shared__ __attribute__((aligned(16))) float lds[4][WLDS]; // 17408 B/block
    // per-wave region: s_A -> [0..1083] (m*68 + n*16 + c); inv overlay -> [0..255]

    const int t = threadIdx.x;
    const int w = t >> 6, lane = t & 63;
    const int atom = blockIdx.x * 4 + w;               // 2500*4 == 10000 exactly
    const int m = lane >> 2, cg = lane & 3;
    const int l = (m >= 9) ? 3 : (m >= 4) ? 2 : (m >= 1) ? 1 : 0;
    const int l4 = l * 4, cg4 = cg * 4;

    const float* gsrc = edat + (size_t)atom * (D_PAD * EDW);

    float acc[4][4];  // [n][j]
    #pragma unroll
    for (int n = 0; n < 4; ++n)
        #pragma unroll
        for (int j = 0; j < 4; ++j) acc[n][j] = 0.f;

    // fully unrolled: 3 independent global loads per slot, no loop-carried deps
    // except acc -- compiler keeps a deep window of loads in flight.
    #pragma unroll
    for (int q = 0; q < D_PAD; ++q) {
        const float* eq = gsrc + q * EDW;
        float shv = eq[m];
        float4 rv = *(const float4*)(eq + 16 + l4);
        float4 hv = *(const float4*)(eq + 32 + cg4);
        float hvj[4] = {hv.x, hv.y, hv.z, hv.w};
        float rvn[4] = {rv.x, rv.y, rv.z, rv.w};
        #pragma unroll
        for (int j = 0; j < 4; ++j) {
            float ww = shv * hvj[j];
            #pragma unroll
            for (int n = 0; n < 4; ++n)
                acc[n][j] = fmaf(ww, rvn[n], acc[n][j]);
        }
    }

    // ---- A -> LDS (same-wave DS is in-order; no barrier needed) ----
    float* s_A = &lds[w][0];
    #pragma unroll
    for (int n = 0; n < 4; ++n)
        *(float4*)&s_A[m * 68 + n * 16 + cg4] =
            make_float4(acc[n][0], acc[n][1], acc[n][2], acc[n][3]);

    const float sc_l[4] = {1.0f, 0.57735026918962576f, 0.44721359549995794f, 0.37796447300922720f};
    float inv4[4];
    #pragma unroll
    for (int i = 0; i < 4; ++i) {
        const int kt = lane * 4 + i;
        const int le = kt >> 6, k64 = kt & 63;
        const int m0 = le * le, m1 = m0 + 2 * le;
        float s = 0.f;
        for (int mm = m0; mm <= m1; ++mm) {
            float v = s_A[mm * 68 + k64];
            s = fmaf(v, v, s);
        }
        inv4[i] = s * sc_l[le];
    }

    if (do_energy) {
        float s = 0.f;
        #pragma unroll
        for (int i = 0; i < 4; ++i) s = fmaf(inv4[i], w_out[lane * 4 + i], s);
        #pragma unroll
        for (int off = 32; off > 0; off >>= 1) s += __shfl_down(s, off);
        if (lane == 0) atomicAdd(&accum[sids[atom]], s + comp_w[species[atom]]);
    } else {
        // per-wave h_new = (inv @ W_inv) * cemb, no cross-wave traffic
        // (overlay is safe: same-wave DS ops execute in program order)
        *(float4*)&lds[w][lane * 4] = make_float4(inv4[0], inv4[1], inv4[2], inv4[3]);
        const int c = lane & 15, q4 = lane >> 4;     // lane covers (c, k-quarter q4)
        const float* wrow = W_invT + c * 256 + q4 * 64;
        float p = 0.f;
        #pragma unroll
        for (int kk = 0; kk < 16; ++kk) {
            float4 iv = *(const float4*)&lds[w][q4 * 64 + kk * 4];
            float4 wv = *(const float4*)(wrow + kk * 4);
            p = fmaf(iv.x, wv.x, p);
            p = fmaf(iv.y, wv.y, p);
            p = fmaf(iv.z, wv.z, p);
            p = fmaf(iv.w, wv.w, p);
        }
        p += __shfl_xor(p, 16);
        p += __shfl_xor(p, 32);
        if (lane < 16) h_out[atom * 16 + c] = p * cemb[atom * 16 + c];
    }
}

__global__ void out_kernel(const float* __restrict__ accum, float* __restrict__ out) {
    int t = threadIdx.x;
    if (t < N_STRUCT) out[t] = accum[t];
}

// ---------------- launch ----------------

extern "C" void kernel_launch(void* const* d_in, const int* in_sizes, int n_in,
                              void* d_out, int out_size, void* d_ws, size_t ws_size,
                              hipStream_t stream) {
    const float* positions = (const float*)d_in[0];
    const float* embed     = (const float*)d_in[1];
    const float* W_rad     = (const float*)d_in[2];
    const float* W_inv1    = (const float*)d_in[3];
    const float* W_inv2    = (const float*)d_in[4];
    const float* w_out     = (const float*)d_in[5];
    const float* comp_w    = (const float*)d_in[6];
    const int* senders    = (const int*)d_in[7];
    const int* receivers  = (const int*)d_in[8];
    const int* species    = (const int*)d_in[9];
    const int* sids       = (const int*)d_in[10];
    float* out = (float*)d_out;

    char* ws = (char*)d_ws;
    size_t off = 0;
    auto alloc = [&](size_t bytes) -> void* {
        void* p = ws + off;
        off = (off + bytes + 255) & ~(size_t)255;
        return p;
    };
    float* edat     = (float*)alloc((size_t)N_SLOTS * EDW * 4);   // 92.2 MB
    float* h0       = (float*)alloc((size_t)N_ATOMS * 16 * 4);
    float* h1       = (float*)alloc((size_t)N_ATOMS * 16 * 4);
    int*   cursor   = (int*)alloc((size_t)N_ATOMS * 4);
    int*   perm     = (int*)alloc((size_t)N_EDGES * 4);
    int*   snd      = (int*)alloc((size_t)N_SLOTS * 4);
    float* accum    = (float*)alloc(8 * 4);
    float* WT1      = (float*)alloc(4096 * 4);
    float* WT2      = (float*)alloc(4096 * 4);

    const int EB = (N_EDGES + 255) / 256;        // 625
    const int HB = (N_ATOMS * 16 + 255) / 256;   // 625
    const int IB = (N_SLOTS + 255) / 256;        // 1875
    const int GB = (N_SLOTS * 4 + 255) / 256;    // 7500

    init_kernel<<<IB, 256, 0, stream>>>(edat, snd, cursor, accum);
    scatter_kernel<<<EB, 256, 0, stream>>>(receivers, cursor, perm);
    edge_geom<<<EB, 256, 0, stream>>>(positions, W_rad, senders, receivers, perm,
                                      edat, snd);
    emb_kernel<<<HB, 256, 0, stream>>>(embed, species, h0);
    transpose_winv<<<32, 256, 0, stream>>>(W_inv1, W_inv2, WT1, WT2);

    // layer 1
    gather_h<<<GB, 256, 0, stream>>>(snd, h0, edat);
    mp_layer<<<N_ATOMS / 4, 256, 0, stream>>>(edat, WT1, h0, h1,
                                              w_out, comp_w, species, sids, accum, 0);
    // layer 2 (energy)
    gather_h<<<GB, 256, 0, stream>>>(snd, h1, edat);
    mp_layer<<<N_ATOMS / 4, 256, 0, stream>>>(edat, WT2, h0, h1,
                                              w_out, comp_w, species, sids, accum, 1);

    out_kernel<<<1, 64, 0, stream>>>(accum, out);
}

// Round 5
// 315.731 us; speedup vs baseline: 1.0615x; 1.0615x over previous
//
#include <hip/hip_runtime.h>

#define N_ATOMS 10000
#define N_EDGES 160000
#define N_STRUCT 8
#define D_PAD 48             // padded slots per atom
#define EDW 32               // floats per slot: [0..15]=sh, [16..31]=R  (hs now gathered live)
#define N_SLOTS (N_ATOMS * D_PAD)
#define SPW 12               // slots per wave (48 / 4 waves)
#define PI_F 3.14159265358979323846f

// ---------------- setup ----------------

__global__ void init_kernel(float* __restrict__ edat, int* __restrict__ snd,
                            int* __restrict__ cursor, float* __restrict__ accum) {
    int i = blockIdx.x * blockDim.x + threadIdx.x;
    if (i < N_SLOTS) {
        float4 z = make_float4(0.f, 0.f, 0.f, 0.f);
        float4* p = (float4*)(edat + (size_t)i * EDW);
        p[0] = z; p[1] = z; p[2] = z; p[3] = z;
        p[4] = z; p[5] = z; p[6] = z; p[7] = z;
        snd[i] = 0;
    }
    if (i < N_ATOMS) cursor[i] = i * D_PAD;
    if (i < N_STRUCT) accum[i] = 0.f;
}

__global__ void scatter_kernel(const int* __restrict__ receivers, int* __restrict__ cursor,
                               int* __restrict__ perm) {
    int e = blockIdx.x * blockDim.x + threadIdx.x;
    if (e < N_EDGES) perm[e] = atomicAdd(&cursor[receivers[e]], 1);
}

__global__ void emb_kernel(const float* __restrict__ embed, const int* __restrict__ species,
                           float* __restrict__ h0) {
    int i = blockIdx.x * blockDim.x + threadIdx.x;
    if (i < N_ATOMS * 16) {
        int a = i >> 4, c = i & 15;
        h0[i] = embed[species[a] * 16 + c];
    }
}

// transpose W_inv [256,16] -> W_invT [16,256] (both layers, one tiny launch)
__global__ void transpose_winv(const float* __restrict__ A, const float* __restrict__ B,
                               float* __restrict__ AT, float* __restrict__ BT) {
    int i = blockIdx.x * blockDim.x + threadIdx.x;
    if (i < 4096) {
        int k = i >> 4, c = i & 15;
        AT[c * 256 + k] = A[i];
    } else if (i < 8192) {
        int j = i - 4096;
        int k = j >> 4, c = j & 15;
        BT[c * 256 + k] = B[j];
    }
}

// ---------------- edge geometry -> padded slots ----------------

__global__ void edge_geom(const float* __restrict__ pos, const float* __restrict__ W_rad,
                          const int* __restrict__ senders, const int* __restrict__ receivers,
                          const int* __restrict__ perm,
                          float* __restrict__ edat, int* __restrict__ snd) {
    int e = blockIdx.x * blockDim.x + threadIdx.x;
    if (e >= N_EDGES) return;
    int s = senders[e], rc = receivers[e];
    int p = perm[e];
    float dx = pos[rc * 3 + 0] - pos[s * 3 + 0];
    float dy = pos[rc * 3 + 1] - pos[s * 3 + 1];
    float dz = pos[rc * 3 + 2] - pos[s * 3 + 2];
    float r = sqrtf(dx * dx + dy * dy + dz * dz);
    float rr = fmaxf(r, 1e-6f);
    float inv = 1.0f / rr;
    float x = dx * inv, y = dy * inv, z = dz * inv;
    float x2 = x * x, y2 = y * y, z2 = z * z;
    float she[16];
    she[0]  = 0.28209479f;
    she[1]  = 0.48860251f * y;
    she[2]  = 0.48860251f * z;
    she[3]  = 0.48860251f * x;
    she[4]  = 1.09254843f * x * y;
    she[5]  = 1.09254843f * y * z;
    she[6]  = 0.31539157f * (3.0f * z2 - 1.0f);
    she[7]  = 1.09254843f * x * z;
    she[8]  = 0.54627422f * (x2 - y2);
    she[9]  = 0.59004359f * y * (3.0f * x2 - y2);
    she[10] = 2.89061144f * x * y * z;
    she[11] = 0.45704579f * y * (5.0f * z2 - 1.0f);
    she[12] = 0.37317633f * z * (5.0f * z2 - 3.0f);
    she[13] = 0.45704579f * x * (5.0f * z2 - 1.0f);
    she[14] = 1.44530572f * z * (x2 - y2);
    she[15] = 0.59004359f * x * (x2 - 3.0f * y2);
    float* ed = edat + (size_t)p * EDW;
    ((float4*)ed)[0] = make_float4(she[0], she[1], she[2], she[3]);
    ((float4*)ed)[1] = make_float4(she[4], she[5], she[6], she[7]);
    ((float4*)ed)[2] = make_float4(she[8], she[9], she[10], she[11]);
    ((float4*)ed)[3] = make_float4(she[12], she[13], she[14], she[15]);
    float fc = 0.5f * (cosf(PI_F * fminf(r * 0.2f, 1.0f)) + 1.0f);
    const float c0 = 0.6324555320336759f; // sqrt(2/5)
    float bfv[8];
    #pragma unroll
    for (int n = 0; n < 8; ++n)
        bfv[n] = c0 * sinf((float)(n + 1) * PI_F * rr * 0.2f) * inv * fc;
    float Re[16];
    #pragma unroll
    for (int l = 0; l < 4; ++l) {
        #pragma unroll
        for (int n = 0; n < 4; ++n) {
            float acc = 0.0f;
            #pragma unroll
            for (int b = 0; b < 8; ++b) acc = fmaf(bfv[b], W_rad[l * 32 + b * 4 + n], acc);
            Re[l * 4 + n] = acc;
        }
    }
    ((float4*)ed)[4] = make_float4(Re[0], Re[1], Re[2], Re[3]);
    ((float4*)ed)[5] = make_float4(Re[4], Re[5], Re[6], Re[7]);
    ((float4*)ed)[6] = make_float4(Re[8], Re[9], Re[10], Re[11]);
    ((float4*)ed)[7] = make_float4(Re[12], Re[13], Re[14], Re[15]);
    snd[p] = s;
}

// ---------------- fused MP layer: one BLOCK per atom, 4 waves x 12 slots ----------------
// R0/R3/R4 (1 wave/atom, 144-load serial chain) all stuck at ~140 us, latency-bound:
// ~4 loads in flight x ~2.5 resident waves/SIMD ~= 0.7 TB/s aggregate. Fix the SHAPE:
// 4x more waves, each with a 37-load chain; h gathered live via snd (L2-resident,
// one cooperative index load + register shfl broadcast -- no gather_h pass, no hs
// in edat). Inner load/FMA pattern identical to R4. Cross-wave reduce in LDS.

__global__ __launch_bounds__(256, 4) void mp_layer(
    const float* __restrict__ edat, const int* __restrict__ snd,
    const float* __restrict__ h_in,
    const float* __restrict__ W_invT,
    const float* __restrict__ cemb, float* __restrict__ h_out,
    const float* __restrict__ w_out, const float* __restrict__ comp_w,
    const int* __restrict__ species, const int* __restrict__ sids,
    float* __restrict__ accum, int do_energy)
{
    __shared__ __attribute__((aligned(16))) float sA[4][1088]; // per-wave partial A: m*68+n*16+c
    __shared__ float sI[272];                                   // inv[256] + wave scratch[16]

    const int t = threadIdx.x;
    const int w = t >> 6, lane = t & 63;
    const int atom = blockIdx.x;                    // 10000 blocks
    const int m = lane >> 2, cg = lane & 3;
    const int l = (m >= 9) ? 3 : (m >= 4) ? 2 : (m >= 1) ? 1 : 0;
    const int l4 = l * 4, cg4 = cg * 4;

    // cooperative sender-index load: lane i holds snd[atom*48+i]; broadcast via shfl
    int sv = 0;
    if (lane < D_PAD) sv = snd[atom * D_PAD + lane];

    const float* strip = edat + (size_t)atom * (D_PAD * EDW);

    float acc[4][4];  // [n][j] ; A[m][n][c=cg*4+j]
    #pragma unroll
    for (int n = 0; n < 4; ++n)
        #pragma unroll
        for (int j = 0; j < 4; ++j) acc[n][j] = 0.f;

    #pragma unroll
    for (int q = 0; q < SPW; ++q) {
        const int slot = w * SPW + q;
        const float* eq = strip + slot * EDW;
        const int s = __shfl(sv, slot);
        float shv = eq[m];
        float4 rv = *(const float4*)(eq + 16 + l4);
        float4 hv = *(const float4*)(h_in + (size_t)s * 16 + cg4);
        float hvj[4] = {hv.x, hv.y, hv.z, hv.w};
        float rvn[4] = {rv.x, rv.y, rv.z, rv.w};
        #pragma unroll
        for (int j = 0; j < 4; ++j) {
            float ww = shv * hvj[j];
            #pragma unroll
            for (int n = 0; n < 4; ++n)
                acc[n][j] = fmaf(ww, rvn[n], acc[n][j]);
        }
    }

    // per-wave partial A -> LDS
    #pragma unroll
    for (int n = 0; n < 4; ++n)
        *(float4*)&sA[w][m * 68 + n * 16 + cg4] =
            make_float4(acc[n][0], acc[n][1], acc[n][2], acc[n][3]);
    __syncthreads();

    // inv: thread t owns k_total = t ; sum 4 wave-partials, then square-accumulate over m in l
    const float sc_l[4] = {1.0f, 0.57735026918962576f, 0.44721359549995794f, 0.37796447300922720f};
    const int le = t >> 6, k64 = t & 63;
    const int m0 = le * le, m1 = m0 + 2 * le;
    float s = 0.f;
    for (int mm = m0; mm <= m1; ++mm) {
        float v = sA[0][mm * 68 + k64] + sA[1][mm * 68 + k64]
                + sA[2][mm * 68 + k64] + sA[3][mm * 68 + k64];
        s = fmaf(v, v, s);
    }
    const float inv_t = s * sc_l[le];

    if (do_energy) {
        float e = inv_t * w_out[t];
        #pragma unroll
        for (int off = 32; off > 0; off >>= 1) e += __shfl_down(e, off);
        if (lane == 0) sI[256 + w] = e;
        __syncthreads();
        if (t == 0) {
            float tot = sI[256] + sI[257] + sI[258] + sI[259];
            atomicAdd(&accum[sids[atom]], tot + comp_w[species[atom]]);
        }
    } else {
        sI[t] = inv_t;
        __syncthreads();
        // h_new[c] = sum_k inv[k] * W_inv[k][c] ; thread t covers (c = t&15, k-quarter kq = t>>4)
        const int c = t & 15, kq = t >> 4;
        const float* wrow = W_invT + c * 256 + kq * 16;
        const float* iv = &sI[kq * 16];
        float p = 0.f;
        #pragma unroll
        for (int i = 0; i < 4; ++i) {
            float4 a = *(const float4*)&iv[i * 4];
            float4 b = *(const float4*)&wrow[i * 4];
            p = fmaf(a.x, b.x, p);
            p = fmaf(a.y, b.y, p);
            p = fmaf(a.z, b.z, p);
            p = fmaf(a.w, b.w, p);
        }
        sA[0][kq * 16 + c] = p;          // sA dead after inv phase; safe post-sync
        __syncthreads();
        if (t < 16) {
            float hsum = 0.f;
            #pragma unroll
            for (int g = 0; g < 16; ++g) hsum += sA[0][g * 16 + t];
            h_out[atom * 16 + t] = hsum * cemb[atom * 16 + t];
        }
    }
}

__global__ void out_kernel(const float* __restrict__ accum, float* __restrict__ out) {
    int t = threadIdx.x;
    if (t < N_STRUCT) out[t] = accum[t];
}

// ---------------- launch ----------------

extern "C" void kernel_launch(void* const* d_in, const int* in_sizes, int n_in,
                              void* d_out, int out_size, void* d_ws, size_t ws_size,
                              hipStream_t stream) {
    const float* positions = (const float*)d_in[0];
    const float* embed     = (const float*)d_in[1];
    const float* W_rad     = (const float*)d_in[2];
    const float* W_inv1    = (const float*)d_in[3];
    const float* W_inv2    = (const float*)d_in[4];
    const float* w_out     = (const float*)d_in[5];
    const float* comp_w    = (const float*)d_in[6];
    const int* senders    = (const int*)d_in[7];
    const int* receivers  = (const int*)d_in[8];
    const int* species    = (const int*)d_in[9];
    const int* sids       = (const int*)d_in[10];
    float* out = (float*)d_out;

    char* ws = (char*)d_ws;
    size_t off = 0;
    auto alloc = [&](size_t bytes) -> void* {
        void* p = ws + off;
        off = (off + bytes + 255) & ~(size_t)255;
        return p;
    };
    float* edat     = (float*)alloc((size_t)N_SLOTS * EDW * 4);   // 61.4 MB
    float* h0       = (float*)alloc((size_t)N_ATOMS * 16 * 4);
    float* h1       = (float*)alloc((size_t)N_ATOMS * 16 * 4);
    int*   cursor   = (int*)alloc((size_t)N_ATOMS * 4);
    int*   perm     = (int*)alloc((size_t)N_EDGES * 4);
    int*   snd      = (int*)alloc((size_t)N_SLOTS * 4);
    float* accum    = (float*)alloc(8 * 4);
    float* WT1      = (float*)alloc(4096 * 4);
    float* WT2      = (float*)alloc(4096 * 4);

    const int EB = (N_EDGES + 255) / 256;        // 625
    const int HB = (N_ATOMS * 16 + 255) / 256;   // 625
    const int IB = (N_SLOTS + 255) / 256;        // 1875

    init_kernel<<<IB, 256, 0, stream>>>(edat, snd, cursor, accum);
    scatter_kernel<<<EB, 256, 0, stream>>>(receivers, cursor, perm);
    edge_geom<<<EB, 256, 0, stream>>>(positions, W_rad, senders, receivers, perm,
                                      edat, snd);
    emb_kernel<<<HB, 256, 0, stream>>>(embed, species, h0);
    transpose_winv<<<32, 256, 0, stream>>>(W_inv1, W_inv2, WT1, WT2);

    // layer 1 (h gathered live from h0)
    mp_layer<<<N_ATOMS, 256, 0, stream>>>(edat, snd, h0, WT1, h0, h1,
                                          w_out, comp_w, species, sids, accum, 0);
    // layer 2 (energy; h gathered live from h1)
    mp_layer<<<N_ATOMS, 256, 0, stream>>>(edat, snd, h1, WT2, h0, h1,
                                          w_out, comp_w, species, sids, accum, 1);

    out_kernel<<<1, 64, 0, stream>>>(accum, out);
}

// Round 6
// 285.943 us; speedup vs baseline: 1.1721x; 1.1042x over previous
//
#include <hip/hip_runtime.h>

#define N_ATOMS 10000
#define N_EDGES 160000
#define N_STRUCT 8
#define D_PAD 48             // max slots per atom; P(Poisson(16) > 48) ~ 2e-7 overall
#define EDW 32               // floats per slot: [0..15]=sh, [16..31]=R  (hs gathered live)
#define N_SLOTS (N_ATOMS * D_PAD)
#define BATCH 6              // slots per register-batch (18 loads in flight)
#define PI_F 3.14159265358979323846f

// ---------------- setup ----------------

__global__ void init_kernel(int* __restrict__ cursor, float* __restrict__ accum) {
    int i = blockIdx.x * blockDim.x + threadIdx.x;
    if (i < N_ATOMS) cursor[i] = i * D_PAD;
    if (i < N_STRUCT) accum[i] = 0.f;
}

__global__ void scatter_kernel(const int* __restrict__ receivers, int* __restrict__ cursor,
                               int* __restrict__ perm) {
    int e = blockIdx.x * blockDim.x + threadIdx.x;
    if (e < N_EDGES) perm[e] = atomicAdd(&cursor[receivers[e]], 1);
}

// zero ONLY the pad slots [cnt, ceil6(cnt)) of each atom (<= 1.4 MB total,
// replaces the old 61 MB whole-edat zero-init)
__global__ void pad_kernel(const int* __restrict__ cursor, float* __restrict__ edat,
                           int* __restrict__ snd) {
    int i = blockIdx.x * blockDim.x + threadIdx.x;
    if (i >= N_ATOMS * BATCH) return;
    int a = i / BATCH, j = i % BATCH;
    int cnt = cursor[a] - a * D_PAD;
    if (cnt > D_PAD) cnt = D_PAD;
    int c6 = (cnt + BATCH - 1) / BATCH * BATCH;
    if (c6 > D_PAD) c6 = D_PAD;
    int slot = cnt + j;
    if (slot < c6) {
        float4 z = make_float4(0.f, 0.f, 0.f, 0.f);
        float4* p = (float4*)(edat + (size_t)(a * D_PAD + slot) * EDW);
        #pragma unroll
        for (int k = 0; k < 8; ++k) p[k] = z;
        snd[a * D_PAD + slot] = 0;
    }
}

__global__ void emb_kernel(const float* __restrict__ embed, const int* __restrict__ species,
                           float* __restrict__ h0) {
    int i = blockIdx.x * blockDim.x + threadIdx.x;
    if (i < N_ATOMS * 16) {
        int a = i >> 4, c = i & 15;
        h0[i] = embed[species[a] * 16 + c];
    }
}

// transpose W_inv [256,16] -> W_invT [16,256] (both layers, one tiny launch)
__global__ void transpose_winv(const float* __restrict__ A, const float* __restrict__ B,
                               float* __restrict__ AT, float* __restrict__ BT) {
    int i = blockIdx.x * blockDim.x + threadIdx.x;
    if (i < 4096) {
        int k = i >> 4, c = i & 15;
        AT[c * 256 + k] = A[i];
    } else if (i < 8192) {
        int j = i - 4096;
        int k = j >> 4, c = j & 15;
        BT[c * 256 + k] = B[j];
    }
}

// ---------------- edge geometry -> slots ----------------

__global__ void edge_geom(const float* __restrict__ pos, const float* __restrict__ W_rad,
                          const int* __restrict__ senders, const int* __restrict__ receivers,
                          const int* __restrict__ perm,
                          float* __restrict__ edat, int* __restrict__ snd) {
    int e = blockIdx.x * blockDim.x + threadIdx.x;
    if (e >= N_EDGES) return;
    int s = senders[e], rc = receivers[e];
    int p = perm[e];
    float dx = pos[rc * 3 + 0] - pos[s * 3 + 0];
    float dy = pos[rc * 3 + 1] - pos[s * 3 + 1];
    float dz = pos[rc * 3 + 2] - pos[s * 3 + 2];
    float r = sqrtf(dx * dx + dy * dy + dz * dz);
    float rr = fmaxf(r, 1e-6f);
    float inv = 1.0f / rr;
    float x = dx * inv, y = dy * inv, z = dz * inv;
    float x2 = x * x, y2 = y * y, z2 = z * z;
    float she[16];
    she[0]  = 0.28209479f;
    she[1]  = 0.48860251f * y;
    she[2]  = 0.48860251f * z;
    she[3]  = 0.48860251f * x;
    she[4]  = 1.09254843f * x * y;
    she[5]  = 1.09254843f * y * z;
    she[6]  = 0.31539157f * (3.0f * z2 - 1.0f);
    she[7]  = 1.09254843f * x * z;
    she[8]  = 0.54627422f * (x2 - y2);
    she[9]  = 0.59004359f * y * (3.0f * x2 - y2);
    she[10] = 2.89061144f * x * y * z;
    she[11] = 0.45704579f * y * (5.0f * z2 - 1.0f);
    she[12] = 0.37317633f * z * (5.0f * z2 - 3.0f);
    she[13] = 0.45704579f * x * (5.0f * z2 - 1.0f);
    she[14] = 1.44530572f * z * (x2 - y2);
    she[15] = 0.59004359f * x * (x2 - 3.0f * y2);
    float* ed = edat + (size_t)p * EDW;
    ((float4*)ed)[0] = make_float4(she[0], she[1], she[2], she[3]);
    ((float4*)ed)[1] = make_float4(she[4], she[5], she[6], she[7]);
    ((float4*)ed)[2] = make_float4(she[8], she[9], she[10], she[11]);
    ((float4*)ed)[3] = make_float4(she[12], she[13], she[14], she[15]);
    float fc = 0.5f * (cosf(PI_F * fminf(r * 0.2f, 1.0f)) + 1.0f);
    const float c0 = 0.6324555320336759f; // sqrt(2/5)
    float bfv[8];
    #pragma unroll
    for (int n = 0; n < 8; ++n)
        bfv[n] = c0 * sinf((float)(n + 1) * PI_F * rr * 0.2f) * inv * fc;
    float Re[16];
    #pragma unroll
    for (int l = 0; l < 4; ++l) {
        #pragma unroll
        for (int n = 0; n < 4; ++n) {
            float acc = 0.0f;
            #pragma unroll
            for (int b = 0; b < 8; ++b) acc = fmaf(bfv[b], W_rad[l * 32 + b * 4 + n], acc);
            Re[l * 4 + n] = acc;
        }
    }
    ((float4*)ed)[4] = make_float4(Re[0], Re[1], Re[2], Re[3]);
    ((float4*)ed)[5] = make_float4(Re[4], Re[5], Re[6], Re[7]);
    ((float4*)ed)[6] = make_float4(Re[8], Re[9], Re[10], Re[11]);
    ((float4*)ed)[7] = make_float4(Re[12], Re[13], Re[14], Re[15]);
    snd[p] = s;
}

// ---------------- fused MP layer: one BLOCK per atom, count-based batches ----------------
// The ~140 us wall across R0/R3/R4/R5 was MLP-per-wave: launch_bounds capped VGPR
// at 64 so only ~4 loads stayed in flight -> ~0.7 TB/s effective. Fix: per 6-slot
// batch, ALL 18 loads go to static register arrays before any FMA (54 VGPR live;
// launch_bounds(256,2) gives the allocator ~128). Waves loop only over the
// ceil(cnt/6) REAL batches (pad slots zeroed by pad_kernel) -> ~20 MB reads, not 61.

__global__ __launch_bounds__(256, 2) void mp_layer(
    const float* __restrict__ edat, const int* __restrict__ snd,
    const int* __restrict__ cursor,
    const float* __restrict__ h_in,
    const float* __restrict__ W_invT,
    const float* __restrict__ cemb, float* __restrict__ h_out,
    const float* __restrict__ w_out, const float* __restrict__ comp_w,
    const int* __restrict__ species, const int* __restrict__ sids,
    float* __restrict__ accum, int do_energy)
{
    __shared__ __attribute__((aligned(16))) float sA[4][1088]; // per-wave partial A: m*68+n*16+c
    __shared__ float sI[272];                                   // inv[256] + wave scratch

    const int t = threadIdx.x;
    const int w = t >> 6, lane = t & 63;
    const int atom = blockIdx.x;                    // 10000 blocks
    const int m = lane >> 2, cg = lane & 3;
    const int l = (m >= 9) ? 3 : (m >= 4) ? 2 : (m >= 1) ? 1 : 0;
    const int l4 = l * 4, cg4 = cg * 4;

    int cnt = cursor[atom] - atom * D_PAD;
    if (cnt > D_PAD) cnt = D_PAD;
    const int nb = (cnt + BATCH - 1) / BATCH;       // real 6-slot batches (pad zeroed)

    // cooperative sender-index load: lane i holds snd[atom*48+i]; broadcast via shfl
    int sv = 0;
    if (lane < D_PAD) sv = snd[atom * D_PAD + lane];

    const float* strip = edat + (size_t)atom * (D_PAD * EDW);

    float acc[4][4];  // [n][j] ; A[m][n][c=cg*4+j]
    #pragma unroll
    for (int n = 0; n < 4; ++n)
        #pragma unroll
        for (int j = 0; j < 4; ++j) acc[n][j] = 0.f;

    for (int b = w; b < nb; b += 4) {
        const int s0 = b * BATCH;
        // phase 1: issue ALL 18 loads of this batch into static register arrays
        float  shv[BATCH];
        float4 rv[BATCH];
        float4 hv[BATCH];
        #pragma unroll
        for (int q = 0; q < BATCH; ++q) {
            const float* eq = strip + (s0 + q) * EDW;
            shv[q] = eq[m];
            rv[q]  = *(const float4*)(eq + 16 + l4);
            hv[q]  = *(const float4*)(h_in + (size_t)__shfl(sv, s0 + q) * 16 + cg4);
        }
        // phase 2: consume
        #pragma unroll
        for (int q = 0; q < BATCH; ++q) {
            float hvj[4] = {hv[q].x, hv[q].y, hv[q].z, hv[q].w};
            float rvn[4] = {rv[q].x, rv[q].y, rv[q].z, rv[q].w};
            #pragma unroll
            for (int j = 0; j < 4; ++j) {
                float ww = shv[q] * hvj[j];
                #pragma unroll
                for (int n = 0; n < 4; ++n)
                    acc[n][j] = fmaf(ww, rvn[n], acc[n][j]);
            }
        }
    }

    // per-wave partial A -> LDS
    #pragma unroll
    for (int n = 0; n < 4; ++n)
        *(float4*)&sA[w][m * 68 + n * 16 + cg4] =
            make_float4(acc[n][0], acc[n][1], acc[n][2], acc[n][3]);
    __syncthreads();

    // inv: thread t owns k_total = t ; sum 4 wave-partials, square-accumulate over m in l
    const float sc_l[4] = {1.0f, 0.57735026918962576f, 0.44721359549995794f, 0.37796447300922720f};
    const int le = t >> 6, k64 = t & 63;
    const int m0 = le * le, m1 = m0 + 2 * le;
    float s = 0.f;
    for (int mm = m0; mm <= m1; ++mm) {
        float v = sA[0][mm * 68 + k64] + sA[1][mm * 68 + k64]
                + sA[2][mm * 68 + k64] + sA[3][mm * 68 + k64];
        s = fmaf(v, v, s);
    }
    const float inv_t = s * sc_l[le];

    if (do_energy) {
        float e = inv_t * w_out[t];
        #pragma unroll
        for (int off = 32; off > 0; off >>= 1) e += __shfl_down(e, off);
        if (lane == 0) sI[256 + w] = e;
        __syncthreads();
        if (t == 0) {
            float tot = sI[256] + sI[257] + sI[258] + sI[259];
            atomicAdd(&accum[sids[atom]], tot + comp_w[species[atom]]);
        }
    } else {
        sI[t] = inv_t;
        __syncthreads();
        // h_new[c] = sum_k inv[k] * W_inv[k][c] ; thread t covers (c = t&15, kq = t>>4)
        const int c = t & 15, kq = t >> 4;
        const float* wrow = W_invT + c * 256 + kq * 16;
        const float* iv = &sI[kq * 16];
        float p = 0.f;
        #pragma unroll
        for (int i = 0; i < 4; ++i) {
            float4 a = *(const float4*)&iv[i * 4];
            float4 bb = *(const float4*)&wrow[i * 4];
            p = fmaf(a.x, bb.x, p);
            p = fmaf(a.y, bb.y, p);
            p = fmaf(a.z, bb.z, p);
            p = fmaf(a.w, bb.w, p);
        }
        sA[0][kq * 16 + c] = p;          // sA dead after inv phase; safe post-sync
        __syncthreads();
        if (t < 16) {
            float hsum = 0.f;
            #pragma unroll
            for (int g = 0; g < 16; ++g) hsum += sA[0][g * 16 + t];
            h_out[atom * 16 + t] = hsum * cemb[atom * 16 + t];
        }
    }
}

__global__ void out_kernel(const float* __restrict__ accum, float* __restrict__ out) {
    int t = threadIdx.x;
    if (t < N_STRUCT) out[t] = accum[t];
}

// ---------------- launch ----------------

extern "C" void kernel_launch(void* const* d_in, const int* in_sizes, int n_in,
                              void* d_out, int out_size, void* d_ws, size_t ws_size,
                              hipStream_t stream) {
    const float* positions = (const float*)d_in[0];
    const float* embed     = (const float*)d_in[1];
    const float* W_rad     = (const float*)d_in[2];
    const float* W_inv1    = (const float*)d_in[3];
    const float* W_inv2    = (const float*)d_in[4];
    const float* w_out     = (const float*)d_in[5];
    const float* comp_w    = (const float*)d_in[6];
    const int* senders    = (const int*)d_in[7];
    const int* receivers  = (const int*)d_in[8];
    const int* species    = (const int*)d_in[9];
    const int* sids       = (const int*)d_in[10];
    float* out = (float*)d_out;

    char* ws = (char*)d_ws;
    size_t off = 0;
    auto alloc = [&](size_t bytes) -> void* {
        void* p = ws + off;
        off = (off + bytes + 255) & ~(size_t)255;
        return p;
    };
    float* edat     = (float*)alloc((size_t)N_SLOTS * EDW * 4);   // 61.4 MB
    float* h0       = (float*)alloc((size_t)N_ATOMS * 16 * 4);
    float* h1       = (float*)alloc((size_t)N_ATOMS * 16 * 4);
    int*   cursor   = (int*)alloc((size_t)N_ATOMS * 4);
    int*   perm     = (int*)alloc((size_t)N_EDGES * 4);
    int*   snd      = (int*)alloc((size_t)N_SLOTS * 4);
    float* accum    = (float*)alloc(8 * 4);
    float* WT1      = (float*)alloc(4096 * 4);
    float* WT2      = (float*)alloc(4096 * 4);

    const int EB = (N_EDGES + 255) / 256;            // 625
    const int HB = (N_ATOMS * 16 + 255) / 256;       // 625
    const int AB = (N_ATOMS + 255) / 256;            // 40
    const int PB = (N_ATOMS * BATCH + 255) / 256;    // 235

    init_kernel<<<AB, 256, 0, stream>>>(cursor, accum);
    scatter_kernel<<<EB, 256, 0, stream>>>(receivers, cursor, perm);
    pad_kernel<<<PB, 256, 0, stream>>>(cursor, edat, snd);
    edge_geom<<<EB, 256, 0, stream>>>(positions, W_rad, senders, receivers, perm,
                                      edat, snd);
    emb_kernel<<<HB, 256, 0, stream>>>(embed, species, h0);
    transpose_winv<<<32, 256, 0, stream>>>(W_inv1, W_inv2, WT1, WT2);

    // layer 1 (h gathered live from h0)
    mp_layer<<<N_ATOMS, 256, 0, stream>>>(edat, snd, cursor, h0, WT1, h0, h1,
                                          w_out, comp_w, species, sids, accum, 0);
    // layer 2 (energy; h gathered live from h1)
    mp_layer<<<N_ATOMS, 256, 0, stream>>>(edat, snd, cursor, h1, WT2, h0, h1,
                                          w_out, comp_w, species, sids, accum, 1);

    out_kernel<<<1, 64, 0, stream>>>(accum, out);
}

// Round 7
// 282.278 us; speedup vs baseline: 1.1873x; 1.0130x over previous
//
#include <hip/hip_runtime.h>

#define N_ATOMS 10000
#define N_EDGES 160000
#define N_STRUCT 8
#define D_PAD 48             // max slots per atom; P(Poisson(16) > 48) ~ 2e-7 overall
#define EDW 32               // floats per slot: [0..15]=sh, [16..31]=R  (hs gathered live)
#define N_SLOTS (N_ATOMS * D_PAD)
#define BATCH 6              // slots per register-batch
#define NWAVES 5000          // persistent waves; each handles atoms wid and wid+5000
#define PI_F 3.14159265358979323846f

// ---------------- setup ----------------

__global__ void init_kernel(int* __restrict__ cursor, float* __restrict__ accum) {
    int i = blockIdx.x * blockDim.x + threadIdx.x;
    if (i < N_ATOMS) cursor[i] = i * D_PAD;
    if (i < N_STRUCT) accum[i] = 0.f;
}

__global__ void scatter_kernel(const int* __restrict__ receivers, int* __restrict__ cursor,
                               int* __restrict__ perm) {
    int e = blockIdx.x * blockDim.x + threadIdx.x;
    if (e < N_EDGES) perm[e] = atomicAdd(&cursor[receivers[e]], 1);
}

// zero ONLY the pad slots [cnt, ceil6(cnt)) of each atom (<= 1.4 MB total)
__global__ void pad_kernel(const int* __restrict__ cursor, float* __restrict__ edat,
                           int* __restrict__ snd) {
    int i = blockIdx.x * blockDim.x + threadIdx.x;
    if (i >= N_ATOMS * BATCH) return;
    int a = i / BATCH, j = i % BATCH;
    int cnt = cursor[a] - a * D_PAD;
    if (cnt > D_PAD) cnt = D_PAD;
    int c6 = (cnt + BATCH - 1) / BATCH * BATCH;
    if (c6 > D_PAD) c6 = D_PAD;
    int slot = cnt + j;
    if (slot < c6) {
        float4 z = make_float4(0.f, 0.f, 0.f, 0.f);
        float4* p = (float4*)(edat + (size_t)(a * D_PAD + slot) * EDW);
        #pragma unroll
        for (int k = 0; k < 8; ++k) p[k] = z;
        snd[a * D_PAD + slot] = 0;
    }
}

__global__ void emb_kernel(const float* __restrict__ embed, const int* __restrict__ species,
                           float* __restrict__ h0) {
    int i = blockIdx.x * blockDim.x + threadIdx.x;
    if (i < N_ATOMS * 16) {
        int a = i >> 4, c = i & 15;
        h0[i] = embed[species[a] * 16 + c];
    }
}

// transpose W_inv [256,16] -> W_invT [16,256] (both layers, one tiny launch)
__global__ void transpose_winv(const float* __restrict__ A, const float* __restrict__ B,
                               float* __restrict__ AT, float* __restrict__ BT) {
    int i = blockIdx.x * blockDim.x + threadIdx.x;
    if (i < 4096) {
        int k = i >> 4, c = i & 15;
        AT[c * 256 + k] = A[i];
    } else if (i < 8192) {
        int j = i - 4096;
        int k = j >> 4, c = j & 15;
        BT[c * 256 + k] = B[j];
    }
}

// ---------------- edge geometry -> slots ----------------

__global__ void edge_geom(const float* __restrict__ pos, const float* __restrict__ W_rad,
                          const int* __restrict__ senders, const int* __restrict__ receivers,
                          const int* __restrict__ perm,
                          float* __restrict__ edat, int* __restrict__ snd) {
    int e = blockIdx.x * blockDim.x + threadIdx.x;
    if (e >= N_EDGES) return;
    int s = senders[e], rc = receivers[e];
    int p = perm[e];
    float dx = pos[rc * 3 + 0] - pos[s * 3 + 0];
    float dy = pos[rc * 3 + 1] - pos[s * 3 + 1];
    float dz = pos[rc * 3 + 2] - pos[s * 3 + 2];
    float r = sqrtf(dx * dx + dy * dy + dz * dz);
    float rr = fmaxf(r, 1e-6f);
    float inv = 1.0f / rr;
    float x = dx * inv, y = dy * inv, z = dz * inv;
    float x2 = x * x, y2 = y * y, z2 = z * z;
    float she[16];
    she[0]  = 0.28209479f;
    she[1]  = 0.48860251f * y;
    she[2]  = 0.48860251f * z;
    she[3]  = 0.48860251f * x;
    she[4]  = 1.09254843f * x * y;
    she[5]  = 1.09254843f * y * z;
    she[6]  = 0.31539157f * (3.0f * z2 - 1.0f);
    she[7]  = 1.09254843f * x * z;
    she[8]  = 0.54627422f * (x2 - y2);
    she[9]  = 0.59004359f * y * (3.0f * x2 - y2);
    she[10] = 2.89061144f * x * y * z;
    she[11] = 0.45704579f * y * (5.0f * z2 - 1.0f);
    she[12] = 0.37317633f * z * (5.0f * z2 - 3.0f);
    she[13] = 0.45704579f * x * (5.0f * z2 - 1.0f);
    she[14] = 1.44530572f * z * (x2 - y2);
    she[15] = 0.59004359f * x * (x2 - 3.0f * y2);
    float* ed = edat + (size_t)p * EDW;
    ((float4*)ed)[0] = make_float4(she[0], she[1], she[2], she[3]);
    ((float4*)ed)[1] = make_float4(she[4], she[5], she[6], she[7]);
    ((float4*)ed)[2] = make_float4(she[8], she[9], she[10], she[11]);
    ((float4*)ed)[3] = make_float4(she[12], she[13], she[14], she[15]);
    float fc = 0.5f * (cosf(PI_F * fminf(r * 0.2f, 1.0f)) + 1.0f);
    const float c0 = 0.6324555320336759f; // sqrt(2/5)
    float bfv[8];
    #pragma unroll
    for (int n = 0; n < 8; ++n)
        bfv[n] = c0 * sinf((float)(n + 1) * PI_F * rr * 0.2f) * inv * fc;
    float Re[16];
    #pragma unroll
    for (int l = 0; l < 4; ++l) {
        #pragma unroll
        for (int n = 0; n < 4; ++n) {
            float acc = 0.0f;
            #pragma unroll
            for (int b = 0; b < 8; ++b) acc = fmaf(bfv[b], W_rad[l * 32 + b * 4 + n], acc);
            Re[l * 4 + n] = acc;
        }
    }
    ((float4*)ed)[4] = make_float4(Re[0], Re[1], Re[2], Re[3]);
    ((float4*)ed)[5] = make_float4(Re[4], Re[5], Re[6], Re[7]);
    ((float4*)ed)[6] = make_float4(Re[8], Re[9], Re[10], Re[11]);
    ((float4*)ed)[7] = make_float4(Re[12], Re[13], Re[14], Re[15]);
    snd[p] = s;
}

// ---------------- fused MP layer: PERSISTENT wave-per-atom, ZERO barriers ----------------
// R0-R6 all hit a ~134 us floor with all-waves-stalled 90% of the time (VALU work
// alone = 14 us). Shared structure of all of them: 10K tiny syncthreads-coupled
// workgroups churning through CUs. This variant removes both suspects in one shot:
//   - 1250 blocks x 4 waves = 5000 waves, ALL resident from t=0 (4.9 blk/CU < 8 cap):
//     no workgroup churn for the whole dispatch.
//   - wave-per-atom with per-wave epilogue (verified in R0/R3): NO __syncthreads at all;
//     waves are fully independent, each serially processing atoms wid and wid+5000.
// Count-based register batches (6 slots x 18 loads) as in R6; pad slots pre-zeroed.

__global__ __launch_bounds__(256, 2) void mp_layer(
    const float* __restrict__ edat, const int* __restrict__ snd,
    const int* __restrict__ cursor,
    const float* __restrict__ h_in,
    const float* __restrict__ W_invT,
    const float* __restrict__ cemb, float* __restrict__ h_out,
    const float* __restrict__ w_out, const float* __restrict__ comp_w,
    const int* __restrict__ species, const int* __restrict__ sids,
    float* __restrict__ accum, int do_energy)
{
    __shared__ __attribute__((aligned(16))) float lds[4][1088]; // per-wave scratch, 17408 B
    // per-wave region: s_A -> [0..1083] (m*68 + n*16 + c), inv overlay -> [0..255]

    const int t = threadIdx.x;
    const int w = t >> 6, lane = t & 63;
    const int wid = blockIdx.x * 4 + w;             // [0, 5000)
    const int m = lane >> 2, cg = lane & 3;
    const int l = (m >= 9) ? 3 : (m >= 4) ? 2 : (m >= 1) ? 1 : 0;
    const int l4 = l * 4, cg4 = cg * 4;
    float* wl = &lds[w][0];

    const float sc_l[4] = {1.0f, 0.57735026918962576f, 0.44721359549995794f, 0.37796447300922720f};

    #pragma unroll
    for (int rep = 0; rep < 2; ++rep) {
        const int atom = wid + rep * NWAVES;        // covers 0..9999 exactly

        int cnt = cursor[atom] - atom * D_PAD;
        if (cnt > D_PAD) cnt = D_PAD;
        const int nb = (cnt + BATCH - 1) / BATCH;   // real 6-slot batches (pad zeroed)

        int sv = 0;
        if (lane < D_PAD) sv = snd[atom * D_PAD + lane];
        const float* strip = edat + (size_t)atom * (D_PAD * EDW);

        float acc[4][4];  // [n][j] ; A[m][n][c=cg*4+j]
        #pragma unroll
        for (int n = 0; n < 4; ++n)
            #pragma unroll
            for (int j = 0; j < 4; ++j) acc[n][j] = 0.f;

        for (int b = 0; b < nb; ++b) {
            const int s0 = b * BATCH;
            float  shv[BATCH];
            float4 rv[BATCH];
            float4 hv[BATCH];
            #pragma unroll
            for (int q = 0; q < BATCH; ++q) {
                const float* eq = strip + (s0 + q) * EDW;
                shv[q] = eq[m];
                rv[q]  = *(const float4*)(eq + 16 + l4);
                hv[q]  = *(const float4*)(h_in + (size_t)__shfl(sv, s0 + q) * 16 + cg4);
            }
            #pragma unroll
            for (int q = 0; q < BATCH; ++q) {
                float hvj[4] = {hv[q].x, hv[q].y, hv[q].z, hv[q].w};
                float rvn[4] = {rv[q].x, rv[q].y, rv[q].z, rv[q].w};
                #pragma unroll
                for (int j = 0; j < 4; ++j) {
                    float ww = shv[q] * hvj[j];
                    #pragma unroll
                    for (int n = 0; n < 4; ++n)
                        acc[n][j] = fmaf(ww, rvn[n], acc[n][j]);
                }
            }
        }

        // ---- per-wave epilogue (same-wave DS is in-order; no barriers) ----
        #pragma unroll
        for (int n = 0; n < 4; ++n)
            *(float4*)&wl[m * 68 + n * 16 + cg4] =
                make_float4(acc[n][0], acc[n][1], acc[n][2], acc[n][3]);

        float inv4[4];
        #pragma unroll
        for (int i = 0; i < 4; ++i) {
            const int kt = lane * 4 + i;
            const int le = kt >> 6, k64 = kt & 63;
            const int m0 = le * le, m1 = m0 + 2 * le;
            float s = 0.f;
            for (int mm = m0; mm <= m1; ++mm) {
                float v = wl[mm * 68 + k64];
                s = fmaf(v, v, s);
            }
            inv4[i] = s * sc_l[le];
        }

        if (do_energy) {
            float s = 0.f;
            #pragma unroll
            for (int i = 0; i < 4; ++i) s = fmaf(inv4[i], w_out[lane * 4 + i], s);
            #pragma unroll
            for (int off = 32; off > 0; off >>= 1) s += __shfl_down(s, off);
            if (lane == 0) atomicAdd(&accum[sids[atom]], s + comp_w[species[atom]]);
        } else {
            // per-wave h_new = (inv @ W_inv) * cemb  (overlay aliases dead s_A region)
            *(float4*)&wl[lane * 4] = make_float4(inv4[0], inv4[1], inv4[2], inv4[3]);
            const int c = lane & 15, q4 = lane >> 4;
            const float* wrow = W_invT + c * 256 + q4 * 64;
            float p = 0.f;
            #pragma unroll
            for (int kk = 0; kk < 16; ++kk) {
                float4 iv = *(const float4*)&wl[q4 * 64 + kk * 4];
                float4 wv = *(const float4*)(wrow + kk * 4);
                p = fmaf(iv.x, wv.x, p);
                p = fmaf(iv.y, wv.y, p);
                p = fmaf(iv.z, wv.z, p);
                p = fmaf(iv.w, wv.w, p);
            }
            p += __shfl_xor(p, 16);
            p += __shfl_xor(p, 32);
            if (lane < 16) h_out[atom * 16 + c] = p * cemb[atom * 16 + c];
        }
    }
}

__global__ void out_kernel(const float* __restrict__ accum, float* __restrict__ out) {
    int t = threadIdx.x;
    if (t < N_STRUCT) out[t] = accum[t];
}

// ---------------- launch ----------------

extern "C" void kernel_launch(void* const* d_in, const int* in_sizes, int n_in,
                              void* d_out, int out_size, void* d_ws, size_t ws_size,
                              hipStream_t stream) {
    const float* positions = (const float*)d_in[0];
    const float* embed     = (const float*)d_in[1];
    const float* W_rad     = (const float*)d_in[2];
    const float* W_inv1    = (const float*)d_in[3];
    const float* W_inv2    = (const float*)d_in[4];
    const float* w_out     = (const float*)d_in[5];
    const float* comp_w    = (const float*)d_in[6];
    const int* senders    = (const int*)d_in[7];
    const int* receivers  = (const int*)d_in[8];
    const int* species    = (const int*)d_in[9];
    const int* sids       = (const int*)d_in[10];
    float* out = (float*)d_out;

    char* ws = (char*)d_ws;
    size_t off = 0;
    auto alloc = [&](size_t bytes) -> void* {
        void* p = ws + off;
        off = (off + bytes + 255) & ~(size_t)255;
        return p;
    };
    float* edat     = (float*)alloc((size_t)N_SLOTS * EDW * 4);   // 61.4 MB
    float* h0       = (float*)alloc((size_t)N_ATOMS * 16 * 4);
    float* h1       = (float*)alloc((size_t)N_ATOMS * 16 * 4);
    int*   cursor   = (int*)alloc((size_t)N_ATOMS * 4);
    int*   perm     = (int*)alloc((size_t)N_EDGES * 4);
    int*   snd      = (int*)alloc((size_t)N_SLOTS * 4);
    float* accum    = (float*)alloc(8 * 4);
    float* WT1      = (float*)alloc(4096 * 4);
    float* WT2      = (float*)alloc(4096 * 4);

    const int EB = (N_EDGES + 255) / 256;            // 625
    const int HB = (N_ATOMS * 16 + 255) / 256;       // 625
    const int AB = (N_ATOMS + 255) / 256;            // 40
    const int PB = (N_ATOMS * BATCH + 255) / 256;    // 235

    init_kernel<<<AB, 256, 0, stream>>>(cursor, accum);
    scatter_kernel<<<EB, 256, 0, stream>>>(receivers, cursor, perm);
    pad_kernel<<<PB, 256, 0, stream>>>(cursor, edat, snd);
    edge_geom<<<EB, 256, 0, stream>>>(positions, W_rad, senders, receivers, perm,
                                      edat, snd);
    emb_kernel<<<HB, 256, 0, stream>>>(embed, species, h0);
    transpose_winv<<<32, 256, 0, stream>>>(W_inv1, W_inv2, WT1, WT2);

    // layer 1 (h gathered live from h0)
    mp_layer<<<NWAVES / 4, 256, 0, stream>>>(edat, snd, cursor, h0, WT1, h0, h1,
                                             w_out, comp_w, species, sids, accum, 0);
    // layer 2 (energy; h gathered live from h1)
    mp_layer<<<NWAVES / 4, 256, 0, stream>>>(edat, snd, cursor, h1, WT2, h0, h1,
                                             w_out, comp_w, species, sids, accum, 1);

    out_kernel<<<1, 64, 0, stream>>>(accum, out);
}